// Round 1
// baseline (523.798 us; speedup 1.0000x reference)
//
#include <hip/hip_runtime.h>
#include <stdint.h>

typedef unsigned short u16;
typedef short bf16x8 __attribute__((ext_vector_type(8)));
typedef float f32x4 __attribute__((ext_vector_type(4)));

#define MFMA16(a, b, c) __builtin_amdgcn_mfma_f32_16x16x32_bf16(a, b, c, 0, 0, 0)

// async global->LDS, 16B per lane. LDS dest must be linear (base + lane*16).
__device__ __forceinline__ void ld_lds16(const void* g, void* l) {
  __builtin_amdgcn_global_load_lds(
      (const __attribute__((address_space(1))) void*)(uint64_t)(uintptr_t)g,
      (__attribute__((address_space(3))) void*)(uint32_t)(uintptr_t)l,
      16, 0, 0);
}

__device__ __forceinline__ u16 f32_to_bf16(float f) {
  uint32_t u = __float_as_uint(f);
  return (u16)((u + 0x7FFFu + ((u >> 16) & 1u)) >> 16);
}

// ---------------- f32 -> bf16 convert ----------------
__global__ void cvt_bf16(const float* __restrict__ in, u16* __restrict__ out, int n4) {
  int i = blockIdx.x * blockDim.x + threadIdx.x;
  int stride = gridDim.x * blockDim.x;
  for (; i < n4; i += stride) {
    float4 v = reinterpret_cast<const float4*>(in)[i];
    ushort4 o;
    o.x = f32_to_bf16(v.x); o.y = f32_to_bf16(v.y);
    o.z = f32_to_bf16(v.z); o.w = f32_to_bf16(v.w);
    reinterpret_cast<ushort4*>(out)[i] = o;
  }
}

// ---------------- NT GEMM: C[M][N] = A[M][K] * B[N][K]^T  (bf16 in, f32 acc)
// BM=BN=128, BK=64, 256 threads (4 waves, 2x2), each wave 64x64 (4x4 MFMA tiles).
// LDS staged via global_load_lds with XOR-swizzled GLOBAL source so swizzled
// ds_read_b128 fragment reads are bank-conflict-free (<=2-way).
template <int OUTF32>
__global__ __launch_bounds__(256, 1)
void gemm_nt(const u16* __restrict__ A, const u16* __restrict__ B,
             void* __restrict__ Cv, int M, int N, int K, float alpha) {
  __shared__ u16 lA[128 * 64];
  __shared__ u16 lB[128 * 64];
  const int tid = threadIdx.x;
  const int lane = tid & 63;
  const int w = tid >> 6;
  const int c = lane & 15, g = lane >> 4;
  const int wm = (w & 1) * 64, wn = (w >> 1) * 64;
  const int m0 = blockIdx.y * 128, n0 = blockIdx.x * 128;
  const int sr = tid >> 3, sc = tid & 7;  // staging row-within-pass / 16B-chunk

  f32x4 acc[4][4] = {};

  for (int k0 = 0; k0 < K; k0 += 64) {
    __syncthreads();
#pragma unroll
    for (int p = 0; p < 4; ++p) {
      int row = p * 32 + sr;
      int gc = sc ^ (row & 7);
      ld_lds16(A + (size_t)(m0 + row) * K + k0 + gc * 8, &lA[row * 64 + sc * 8]);
    }
#pragma unroll
    for (int p = 0; p < 4; ++p) {
      int row = p * 32 + sr;
      int gc = sc ^ (row & 7);
      ld_lds16(B + (size_t)(n0 + row) * K + k0 + gc * 8, &lB[row * 64 + sc * 8]);
    }
    __syncthreads();
#pragma unroll
    for (int kc = 0; kc < 2; ++kc) {
      bf16x8 a[4], b[4];
#pragma unroll
      for (int t = 0; t < 4; ++t) {
        int row = wm + t * 16 + c;
        int ch = (g + 4 * kc) ^ (row & 7);
        a[t] = *(const bf16x8*)&lA[row * 64 + ch * 8];
      }
#pragma unroll
      for (int t = 0; t < 4; ++t) {
        int row = wn + t * 16 + c;
        int ch = (g + 4 * kc) ^ (row & 7);
        b[t] = *(const bf16x8*)&lB[row * 64 + ch * 8];
      }
#pragma unroll
      for (int i = 0; i < 4; ++i)
#pragma unroll
        for (int j = 0; j < 4; ++j)
          acc[i][j] = MFMA16(a[i], b[j], acc[i][j]);
    }
  }

  // epilogue: D row = (lane>>4)*4 + r, col = lane&15 (m89-verified layout)
#pragma unroll
  for (int i = 0; i < 4; ++i)
#pragma unroll
    for (int j = 0; j < 4; ++j)
#pragma unroll
      for (int r = 0; r < 4; ++r) {
        int mm = m0 + wm + i * 16 + g * 4 + r;
        int nn = n0 + wn + j * 16 + c;
        float v = acc[i][j][r] * alpha;
        if (OUTF32)
          ((float*)Cv)[(size_t)mm * N + nn] = v;
        else
          ((u16*)Cv)[(size_t)mm * N + nn] = f32_to_bf16(v);
      }
}

// ---------------- fused flash attention ----------------
// Q bf16 [2048][2048] (pre-scaled by log2e/sqrt(128)), K bf16 [8192][512],
// VT bf16 [512][8192], O bf16 [2048][2048]. Mask: j <= i + 6144.
// grid 256 = 16 heads x 16 q-blocks(128); 8 waves x 16 q-rows each; KB=64.
__global__ __launch_bounds__(512, 1)
void attn_kernel(const u16* __restrict__ Q, const u16* __restrict__ Kg,
                 const u16* __restrict__ VT, u16* __restrict__ O) {
  __shared__ u16 lK[64 * 128];    // [j][d], chunk^=(j&15) swizzle
  __shared__ u16 lV[128 * 64];    // [d][j], chunk^=(d&7) swizzle
  __shared__ u16 lP[8][16 * 72];  // per-wave P^T bounce, row stride 72

  const int tid = threadIdx.x;
  const int w = tid >> 6, lane = tid & 63;
  const int c = lane & 15, g = lane >> 4;
  const int qb = blockIdx.x & 15, h = blockIdx.x >> 4;
  const int hk = h >> 2;          // GQA: 4 query heads per kv head
  const int i0 = qb * 128;
  const int qrow = i0 + w * 16;

  // Q fragments: lane holds Q[q=c][d = kc*32 + g*8 .. +7]
  bf16x8 qf[4];
#pragma unroll
  for (int kc = 0; kc < 4; ++kc)
    qf[kc] = *(const bf16x8*)&Q[(size_t)(qrow + c) * 2048 + h * 128 + kc * 32 + g * 8];

  f32x4 accO[8] = {};
  float mrow[4], srow[4];
#pragma unroll
  for (int r = 0; r < 4; ++r) { mrow[r] = -1e30f; srow[r] = 0.f; }

  const int ntiles = (i0 + 6272) >> 6;
  for (int t = 0; t < ntiles; ++t) {
    const int j0 = t * 64;
    __syncthreads();
    // stage K tile [64][128]: 1024 x 16B chunks, 2 passes
#pragma unroll
    for (int p = 0; p < 2; ++p) {
      int idx = p * 512 + tid;
      int row = idx >> 4, cc = idx & 15;
      int gc = cc ^ (row & 15);
      ld_lds16(Kg + (size_t)(j0 + row) * 512 + hk * 128 + gc * 8, &lK[row * 128 + cc * 8]);
    }
    // stage V^T tile [128][64]
#pragma unroll
    for (int p = 0; p < 2; ++p) {
      int idx = p * 512 + tid;
      int row = idx >> 3, cc = idx & 7;
      int gc = cc ^ (row & 7);
      ld_lds16(VT + (size_t)(hk * 128 + row) * 8192 + j0 + gc * 8, &lV[row * 64 + cc * 8]);
    }
    __syncthreads();

    // S = Q K^T : s[jt] holds S[q=g*4+r][j=c+16*jt] (already in log2 domain)
    f32x4 s[4] = {};
#pragma unroll
    for (int kc = 0; kc < 4; ++kc)
#pragma unroll
      for (int jt = 0; jt < 4; ++jt) {
        int row = jt * 16 + c;
        int ch = (g + 4 * kc) ^ (row & 15);
        bf16x8 kf = *(const bf16x8*)&lK[row * 128 + ch * 8];
        s[jt] = MFMA16(qf[kc], kf, s[jt]);
      }

    if (j0 + 63 > i0 + 6144) {  // boundary tiles: apply causal-offset mask
#pragma unroll
      for (int jt = 0; jt < 4; ++jt)
#pragma unroll
        for (int r = 0; r < 4; ++r) {
          int jg = j0 + jt * 16 + c;
          if (jg > qrow + g * 4 + r + 6144) s[jt][r] = -1e30f;
        }
    }

    // online softmax (base 2), rows q = qrow + g*4 + r
    float p_[4][4], al[4];
#pragma unroll
    for (int r = 0; r < 4; ++r) {
      float tm = fmaxf(fmaxf(s[0][r], s[1][r]), fmaxf(s[2][r], s[3][r]));
#pragma unroll
      for (int mk = 1; mk < 16; mk <<= 1) tm = fmaxf(tm, __shfl_xor(tm, mk));
      float mnew = fmaxf(mrow[r], tm);
      al[r] = exp2f(mrow[r] - mnew);
      mrow[r] = mnew;
      float ts = 0.f;
#pragma unroll
      for (int jt = 0; jt < 4; ++jt) {
        float pv = exp2f(s[jt][r] - mnew);
        p_[jt][r] = pv;
        ts += pv;
      }
#pragma unroll
      for (int mk = 1; mk < 16; mk <<= 1) ts += __shfl_xor(ts, mk);
      srow[r] = srow[r] * al[r] + ts;
    }
#pragma unroll
    for (int dt = 0; dt < 8; ++dt)
#pragma unroll
      for (int r = 0; r < 4; ++r) accO[dt][r] *= al[r];

    // P -> per-wave LDS (transpose to A-fragment layout)
#pragma unroll
    for (int jt = 0; jt < 4; ++jt)
#pragma unroll
      for (int r = 0; r < 4; ++r)
        lP[w][(g * 4 + r) * 72 + jt * 16 + c] = f32_to_bf16(p_[jt][r]);

    bf16x8 pa[2];
#pragma unroll
    for (int ch2 = 0; ch2 < 2; ++ch2)
      pa[ch2] = *(const bf16x8*)&lP[w][c * 72 + ch2 * 32 + g * 8];

    // O += P V : B-frag from V^T tile (lane holds V[j][d=c+16*dt])
#pragma unroll
    for (int dt = 0; dt < 8; ++dt)
#pragma unroll
      for (int ch2 = 0; ch2 < 2; ++ch2) {
        int row = dt * 16 + c;
        int vch = (g + 4 * ch2) ^ (row & 7);
        bf16x8 vf = *(const bf16x8*)&lV[row * 64 + vch * 8];
        accO[dt] = MFMA16(pa[ch2], vf, accO[dt]);
      }
  }

  // epilogue: normalize and store O[q][h*128 + d]
#pragma unroll
  for (int r = 0; r < 4; ++r) {
    float inv = 1.f / srow[r];
#pragma unroll
    for (int dt = 0; dt < 8; ++dt)
      O[(size_t)(qrow + g * 4 + r) * 2048 + h * 128 + dt * 16 + c] =
          f32_to_bf16(accO[dt][r] * inv);
  }
}

// ---------------- launch ----------------
extern "C" void kernel_launch(void* const* d_in, const int* in_sizes, int n_in,
                              void* d_out, int out_size, void* d_ws, size_t ws_size,
                              hipStream_t stream) {
  (void)in_sizes; (void)n_in; (void)out_size; (void)ws_size;
  const float* xq = (const float*)d_in[0];   // [2048][2048]
  const float* xkv = (const float*)d_in[1];  // [8192][2048]
  const float* Wq = (const float*)d_in[2];   // [2048][2048]
  const float* Wk = (const float*)d_in[3];   // [512][2048]
  const float* Wv = (const float*)d_in[4];   // [512][2048]
  const float* Wo = (const float*)d_in[5];   // [2048][2048]

  u16* ws = (u16*)d_ws;
  const size_t M1 = 1024 * 1024;
  u16* xq_b  = ws;             // 4M elems
  u16* xkv_b = ws + 4 * M1;    // 16M
  u16* wq_b  = ws + 20 * M1;   // 4M
  u16* wk_b  = ws + 24 * M1;   // 1M
  u16* wv_b  = ws + 25 * M1;   // 1M
  u16* wo_b  = ws + 26 * M1;   // 4M
  u16* Qb    = ws + 30 * M1;   // 4M  (pre-scaled by log2e/sqrt(D))
  u16* Kb    = ws + 34 * M1;   // 4M  [8192][512]
  u16* VTb   = ws + 38 * M1;   // 4M  [512][8192]
  u16* Ob    = ws + 42 * M1;   // 4M  -> 46M elems = 92MB total

  cvt_bf16<<<1024, 256, 0, stream>>>(xq, xq_b, (int)(4 * M1 / 4));
  cvt_bf16<<<1024, 256, 0, stream>>>(xkv, xkv_b, (int)(16 * M1 / 4));
  cvt_bf16<<<1024, 256, 0, stream>>>(Wq, wq_b, (int)(4 * M1 / 4));
  cvt_bf16<<<1024, 256, 0, stream>>>(Wk, wk_b, (int)(1 * M1 / 4));
  cvt_bf16<<<1024, 256, 0, stream>>>(Wv, wv_b, (int)(1 * M1 / 4));
  cvt_bf16<<<1024, 256, 0, stream>>>(Wo, wo_b, (int)(4 * M1 / 4));

  // Q = x_q Wq^T (scaled);  K = x_kv Wk^T;  V^T = Wv x_kv^T (operand swap)
  gemm_nt<0><<<dim3(16, 16), 256, 0, stream>>>(xq_b, wq_b, Qb, 2048, 2048, 2048, 0.12751743f);
  gemm_nt<0><<<dim3(4, 64), 256, 0, stream>>>(xkv_b, wk_b, Kb, 8192, 512, 2048, 1.0f);
  gemm_nt<0><<<dim3(64, 4), 256, 0, stream>>>(wv_b, xkv_b, VTb, 512, 8192, 2048, 1.0f);

  attn_kernel<<<256, 512, 0, stream>>>(Qb, Kb, VTb, Ob);

  // out = O Wo^T (f32 output)
  gemm_nt<1><<<dim3(16, 16), 256, 0, stream>>>(Ob, wo_b, d_out, 2048, 2048, 2048, 1.0f);
}

// Round 2
// 521.823 us; speedup vs baseline: 1.0038x; 1.0038x over previous
//
#include <hip/hip_runtime.h>
#include <stdint.h>

typedef unsigned short u16;
typedef short bf16x8 __attribute__((ext_vector_type(8)));
typedef float f32x4 __attribute__((ext_vector_type(4)));

#define MFMA16(a, b, c) __builtin_amdgcn_mfma_f32_16x16x32_bf16(a, b, c, 0, 0, 0)

// async global->LDS, 16B per lane. LDS dest must be linear (base + lane*16).
__device__ __forceinline__ void ld_lds16(const void* g, void* l) {
  __builtin_amdgcn_global_load_lds(
      (const __attribute__((address_space(1))) void*)(uint64_t)(uintptr_t)g,
      (__attribute__((address_space(3))) void*)(uint32_t)(uintptr_t)l,
      16, 0, 0);
}

__device__ __forceinline__ u16 f32_to_bf16(float f) {
  uint32_t u = __float_as_uint(f);
  return (u16)((u + 0x7FFFu + ((u >> 16) & 1u)) >> 16);
}

// ---------------- f32 -> bf16 convert ----------------
__global__ void cvt_bf16(const float* __restrict__ in, u16* __restrict__ out, int n4) {
  int i = blockIdx.x * blockDim.x + threadIdx.x;
  int stride = gridDim.x * blockDim.x;
  for (; i < n4; i += stride) {
    float4 v = reinterpret_cast<const float4*>(in)[i];
    ushort4 o;
    o.x = f32_to_bf16(v.x); o.y = f32_to_bf16(v.y);
    o.z = f32_to_bf16(v.z); o.w = f32_to_bf16(v.w);
    reinterpret_cast<ushort4*>(out)[i] = o;
  }
}

// ---------------- NT GEMM: C[M][N] = A[M][K] * B[N][K]^T  (bf16 in, f32 acc)
template <int OUTF32>
__global__ __launch_bounds__(256, 1)
void gemm_nt(const u16* __restrict__ A, const u16* __restrict__ B,
             void* __restrict__ Cv, int M, int N, int K, float alpha) {
  __shared__ u16 lA[128 * 64];
  __shared__ u16 lB[128 * 64];
  const int tid = threadIdx.x;
  const int lane = tid & 63;
  const int w = tid >> 6;
  const int c = lane & 15, g = lane >> 4;
  const int wm = (w & 1) * 64, wn = (w >> 1) * 64;
  const int m0 = blockIdx.y * 128, n0 = blockIdx.x * 128;
  const int sr = tid >> 3, sc = tid & 7;

  f32x4 acc[4][4] = {};

  for (int k0 = 0; k0 < K; k0 += 64) {
    __syncthreads();
#pragma unroll
    for (int p = 0; p < 4; ++p) {
      int row = p * 32 + sr;
      int gc = sc ^ (row & 7);
      ld_lds16(A + (size_t)(m0 + row) * K + k0 + gc * 8, &lA[row * 64 + sc * 8]);
    }
#pragma unroll
    for (int p = 0; p < 4; ++p) {
      int row = p * 32 + sr;
      int gc = sc ^ (row & 7);
      ld_lds16(B + (size_t)(n0 + row) * K + k0 + gc * 8, &lB[row * 64 + sc * 8]);
    }
    __syncthreads();
#pragma unroll
    for (int kc = 0; kc < 2; ++kc) {
      bf16x8 a[4], b[4];
#pragma unroll
      for (int t = 0; t < 4; ++t) {
        int row = wm + t * 16 + c;
        int ch = (g + 4 * kc) ^ (row & 7);
        a[t] = *(const bf16x8*)&lA[row * 64 + ch * 8];
      }
#pragma unroll
      for (int t = 0; t < 4; ++t) {
        int row = wn + t * 16 + c;
        int ch = (g + 4 * kc) ^ (row & 7);
        b[t] = *(const bf16x8*)&lB[row * 64 + ch * 8];
      }
#pragma unroll
      for (int i = 0; i < 4; ++i)
#pragma unroll
        for (int j = 0; j < 4; ++j)
          acc[i][j] = MFMA16(a[i], b[j], acc[i][j]);
    }
  }

#pragma unroll
  for (int i = 0; i < 4; ++i)
#pragma unroll
    for (int j = 0; j < 4; ++j)
#pragma unroll
      for (int r = 0; r < 4; ++r) {
        int mm = m0 + wm + i * 16 + g * 4 + r;
        int nn = n0 + wn + j * 16 + c;
        float v = acc[i][j][r] * alpha;
        if (OUTF32)
          ((float*)Cv)[(size_t)mm * N + nn] = v;
        else
          ((u16*)Cv)[(size_t)mm * N + nn] = f32_to_bf16(v);
      }
}

// ---------------- fused flash attention v2 ----------------
// Q bf16 [2048][2048] (pre-scaled by log2e/sqrt(128)), K bf16 [8192][512],
// VT bf16 [512][8192], O bf16 [2048][2048]. Mask: j <= i + 6144.
// grid 512 = 16 heads x 32 q-blocks(64 rows); 4 waves x 16 q-rows; KB=64.
// Double-buffered K/V via global_load_lds + counted vmcnt + raw s_barrier.
__global__ __launch_bounds__(256, 2)
void attn_kernel(const u16* __restrict__ Q, const u16* __restrict__ Kg,
                 const u16* __restrict__ VT, u16* __restrict__ O) {
  __shared__ u16 lK[2][64 * 128];  // [j][d], chunk^=(j&15) swizzle
  __shared__ u16 lV[2][128 * 64];  // [d][j], chunk^=(d&7) swizzle
  __shared__ u16 lP[4][16 * 72];   // per-wave P^T bounce, row stride 72

  const int tid = threadIdx.x;
  const int w = tid >> 6, lane = tid & 63;
  const int c = lane & 15, g = lane >> 4;
  const int qb = blockIdx.x & 31, h = blockIdx.x >> 5;
  const int hk = h >> 2;  // GQA: 4 query heads per kv head
  const int i0 = qb * 64;
  const int qrow = i0 + w * 16;

  // Q fragments: lane holds Q[q=c][d = kc*32 + g*8 .. +7]
  bf16x8 qf[4];
#pragma unroll
  for (int kc = 0; kc < 4; ++kc)
    qf[kc] = *(const bf16x8*)&Q[(size_t)(qrow + c) * 2048 + h * 128 + kc * 32 + g * 8];

  f32x4 accO[8] = {};
  float mrow[4], srow[4];
#pragma unroll
  for (int r = 0; r < 4; ++r) { mrow[r] = -1e30f; srow[r] = 0.f; }

  const int nt = (i0 + 6144 + 64) >> 6;

  // stage tile t into buffer buf: 8 global_load_lds per thread (K:4, V:4)
  auto stage = [&](int buf, int t) {
    const int j0 = t << 6;
#pragma unroll
    for (int p = 0; p < 4; ++p) {
      int idx = p * 256 + tid;
      int row = idx >> 4, cc = idx & 15;
      int gc = cc ^ (row & 15);
      ld_lds16(Kg + (size_t)(j0 + row) * 512 + hk * 128 + gc * 8,
               &lK[buf][row * 128 + cc * 8]);
    }
#pragma unroll
    for (int p = 0; p < 4; ++p) {
      int idx = p * 256 + tid;
      int row = idx >> 3, cc = idx & 7;
      int gc = cc ^ (row & 7);
      ld_lds16(VT + (size_t)(hk * 128 + row) * 8192 + j0 + gc * 8,
               &lV[buf][row * 64 + cc * 8]);
    }
  };

  stage(0, 0);  // prologue

  for (int t = 0; t < nt; ++t) {
    const int curb = t & 1;
    const int j0 = t << 6;
    if (t + 1 < nt) {
      stage(curb ^ 1, t + 1);
      asm volatile("s_waitcnt vmcnt(8)" ::: "memory");  // tile t's 8 loads done
    } else {
      asm volatile("s_waitcnt vmcnt(0)" ::: "memory");
    }
    __builtin_amdgcn_s_barrier();

    // S = Q K^T : s[jt] holds S[q=g*4+r][j=c+16*jt] (log2 domain)
    f32x4 s[4] = {};
    __builtin_amdgcn_s_setprio(1);
#pragma unroll
    for (int kc = 0; kc < 4; ++kc)
#pragma unroll
      for (int jt = 0; jt < 4; ++jt) {
        int row = jt * 16 + c;
        int ch = (g + 4 * kc) ^ (row & 15);
        bf16x8 kf = *(const bf16x8*)&lK[curb][row * 128 + ch * 8];
        s[jt] = MFMA16(qf[kc], kf, s[jt]);
      }
    __builtin_amdgcn_s_setprio(0);

    if (j0 + 63 > i0 + 6144) {  // boundary tile: causal-offset mask
#pragma unroll
      for (int jt = 0; jt < 4; ++jt)
#pragma unroll
        for (int r = 0; r < 4; ++r) {
          int jg = j0 + jt * 16 + c;
          if (jg > qrow + g * 4 + r + 6144) s[jt][r] = -1e30f;
        }
    }

    // tile max per row
    float tm[4];
#pragma unroll
    for (int r = 0; r < 4; ++r) {
      float v = fmaxf(fmaxf(s[0][r], s[1][r]), fmaxf(s[2][r], s[3][r]));
#pragma unroll
      for (int mk = 1; mk < 16; mk <<= 1) v = fmaxf(v, __shfl_xor(v, mk));
      tm[r] = v;
    }
    // defer-max: skip rescale when max growth <= 8 (log2 domain; P <= 256)
    float dmax = fmaxf(fmaxf(tm[0] - mrow[0], tm[1] - mrow[1]),
                       fmaxf(tm[2] - mrow[2], tm[3] - mrow[3]));
    if (!__all(dmax <= 8.0f)) {
#pragma unroll
      for (int r = 0; r < 4; ++r) {
        float mnew = fmaxf(mrow[r], tm[r]);
        float al = exp2f(mrow[r] - mnew);
        mrow[r] = mnew;
        srow[r] *= al;
#pragma unroll
        for (int dt = 0; dt < 8; ++dt) accO[dt][r] *= al;
      }
    }
    // P = exp2(S - m), row sums
    float p_[4][4];
#pragma unroll
    for (int r = 0; r < 4; ++r) {
      float ts = 0.f;
#pragma unroll
      for (int jt = 0; jt < 4; ++jt) {
        float pv = exp2f(s[jt][r] - mrow[r]);
        p_[jt][r] = pv;
        ts += pv;
      }
#pragma unroll
      for (int mk = 1; mk < 16; mk <<= 1) ts += __shfl_xor(ts, mk);
      srow[r] += ts;
    }

    // P -> per-wave LDS (transpose to A-fragment layout)
#pragma unroll
    for (int jt = 0; jt < 4; ++jt)
#pragma unroll
      for (int r = 0; r < 4; ++r)
        lP[w][(g * 4 + r) * 72 + jt * 16 + c] = f32_to_bf16(p_[jt][r]);

    bf16x8 pa[2];
#pragma unroll
    for (int ch2 = 0; ch2 < 2; ++ch2)
      pa[ch2] = *(const bf16x8*)&lP[w][c * 72 + ch2 * 32 + g * 8];

    // O += P V
    __builtin_amdgcn_s_setprio(1);
#pragma unroll
    for (int dt = 0; dt < 8; ++dt)
#pragma unroll
      for (int ch2 = 0; ch2 < 2; ++ch2) {
        int row = dt * 16 + c;
        int vch = (g + 4 * ch2) ^ (row & 7);
        bf16x8 vf = *(const bf16x8*)&lV[curb][row * 64 + vch * 8];
        accO[dt] = MFMA16(pa[ch2], vf, accO[dt]);
      }
    __builtin_amdgcn_s_setprio(0);

    __builtin_amdgcn_s_barrier();
  }

  // epilogue: normalize and store O[q][h*128 + d]
#pragma unroll
  for (int r = 0; r < 4; ++r) {
    float inv = 1.f / srow[r];
#pragma unroll
    for (int dt = 0; dt < 8; ++dt)
      O[(size_t)(qrow + g * 4 + r) * 2048 + h * 128 + dt * 16 + c] =
          f32_to_bf16(accO[dt][r] * inv);
  }
}

// ---------------- launch ----------------
extern "C" void kernel_launch(void* const* d_in, const int* in_sizes, int n_in,
                              void* d_out, int out_size, void* d_ws, size_t ws_size,
                              hipStream_t stream) {
  (void)in_sizes; (void)n_in; (void)out_size; (void)ws_size;
  const float* xq = (const float*)d_in[0];   // [2048][2048]
  const float* xkv = (const float*)d_in[1];  // [8192][2048]
  const float* Wq = (const float*)d_in[2];   // [2048][2048]
  const float* Wk = (const float*)d_in[3];   // [512][2048]
  const float* Wv = (const float*)d_in[4];   // [512][2048]
  const float* Wo = (const float*)d_in[5];   // [2048][2048]

  u16* ws = (u16*)d_ws;
  const size_t M1 = 1024 * 1024;
  u16* xq_b  = ws;             // 4M elems
  u16* xkv_b = ws + 4 * M1;    // 16M
  u16* wq_b  = ws + 20 * M1;   // 4M
  u16* wk_b  = ws + 24 * M1;   // 1M
  u16* wv_b  = ws + 25 * M1;   // 1M
  u16* wo_b  = ws + 26 * M1;   // 4M
  u16* Qb    = ws + 30 * M1;   // 4M  (pre-scaled by log2e/sqrt(D))
  u16* Kb    = ws + 34 * M1;   // 4M  [8192][512]
  u16* VTb   = ws + 38 * M1;   // 4M  [512][8192]
  u16* Ob    = ws + 42 * M1;   // 4M

  cvt_bf16<<<1024, 256, 0, stream>>>(xq, xq_b, (int)(4 * M1 / 4));
  cvt_bf16<<<1024, 256, 0, stream>>>(xkv, xkv_b, (int)(16 * M1 / 4));
  cvt_bf16<<<1024, 256, 0, stream>>>(Wq, wq_b, (int)(4 * M1 / 4));
  cvt_bf16<<<1024, 256, 0, stream>>>(Wk, wk_b, (int)(1 * M1 / 4));
  cvt_bf16<<<1024, 256, 0, stream>>>(Wv, wv_b, (int)(1 * M1 / 4));
  cvt_bf16<<<1024, 256, 0, stream>>>(Wo, wo_b, (int)(4 * M1 / 4));

  // Q = x_q Wq^T (scaled);  K = x_kv Wk^T;  V^T = Wv x_kv^T (operand swap)
  gemm_nt<0><<<dim3(16, 16), 256, 0, stream>>>(xq_b, wq_b, Qb, 2048, 2048, 2048, 0.12751743f);
  gemm_nt<0><<<dim3(4, 64), 256, 0, stream>>>(xkv_b, wk_b, Kb, 8192, 512, 2048, 1.0f);
  gemm_nt<0><<<dim3(64, 4), 256, 0, stream>>>(wv_b, xkv_b, VTb, 512, 8192, 2048, 1.0f);

  attn_kernel<<<512, 256, 0, stream>>>(Qb, Kb, VTb, Ob);

  // out = O Wo^T (f32 output)
  gemm_nt<1><<<dim3(16, 16), 256, 0, stream>>>(Ob, wo_b, d_out, 2048, 2048, 2048, 1.0f);
}

// Round 3
// 398.252 us; speedup vs baseline: 1.3152x; 1.3103x over previous
//
#include <hip/hip_runtime.h>
#include <stdint.h>

typedef unsigned short u16;
typedef short bf16x8 __attribute__((ext_vector_type(8)));
typedef float f32x4 __attribute__((ext_vector_type(4)));

#define MFMA16(a, b, c) __builtin_amdgcn_mfma_f32_16x16x32_bf16(a, b, c, 0, 0, 0)

// async global->LDS, 16B per lane. LDS dest must be linear (base + lane*16).
__device__ __forceinline__ void ld_lds16(const void* g, void* l) {
  __builtin_amdgcn_global_load_lds(
      (const __attribute__((address_space(1))) void*)(uint64_t)(uintptr_t)g,
      (__attribute__((address_space(3))) void*)(uint32_t)(uintptr_t)l,
      16, 0, 0);
}

__device__ __forceinline__ u16 f32_to_bf16(float f) {
  uint32_t u = __float_as_uint(f);
  return (u16)((u + 0x7FFFu + ((u >> 16) & 1u)) >> 16);
}

__device__ __forceinline__ uint32_t cvt_pk_bf16(float a, float b) {
  uint32_t r;
  asm("v_cvt_pk_bf16_f32 %0, %1, %2" : "=v"(r) : "v"(a), "v"(b));
  return r;
}

// ---------------- f32 -> bf16 convert ----------------
__global__ void cvt_bf16(const float* __restrict__ in, u16* __restrict__ out, int n4) {
  int i = blockIdx.x * blockDim.x + threadIdx.x;
  int stride = gridDim.x * blockDim.x;
  for (; i < n4; i += stride) {
    float4 v = reinterpret_cast<const float4*>(in)[i];
    ushort4 o;
    o.x = f32_to_bf16(v.x); o.y = f32_to_bf16(v.y);
    o.z = f32_to_bf16(v.z); o.w = f32_to_bf16(v.w);
    reinterpret_cast<ushort4*>(out)[i] = o;
  }
}

// ---------------- NT GEMM: C[M][N] = A[M][K] * B[N][K]^T  (bf16 in, f32 acc)
template <int OUTF32>
__global__ __launch_bounds__(256, 1)
void gemm_nt(const u16* __restrict__ A, const u16* __restrict__ B,
             void* __restrict__ Cv, int M, int N, int K, float alpha) {
  __shared__ u16 lA[128 * 64];
  __shared__ u16 lB[128 * 64];
  const int tid = threadIdx.x;
  const int lane = tid & 63;
  const int w = tid >> 6;
  const int c = lane & 15, g = lane >> 4;
  const int wm = (w & 1) * 64, wn = (w >> 1) * 64;
  const int m0 = blockIdx.y * 128, n0 = blockIdx.x * 128;
  const int sr = tid >> 3, sc = tid & 7;

  f32x4 acc[4][4] = {};

  for (int k0 = 0; k0 < K; k0 += 64) {
    __syncthreads();
#pragma unroll
    for (int p = 0; p < 4; ++p) {
      int row = p * 32 + sr;
      int gc = sc ^ (row & 7);
      ld_lds16(A + (size_t)(m0 + row) * K + k0 + gc * 8, &lA[row * 64 + sc * 8]);
    }
#pragma unroll
    for (int p = 0; p < 4; ++p) {
      int row = p * 32 + sr;
      int gc = sc ^ (row & 7);
      ld_lds16(B + (size_t)(n0 + row) * K + k0 + gc * 8, &lB[row * 64 + sc * 8]);
    }
    __syncthreads();
#pragma unroll
    for (int kc = 0; kc < 2; ++kc) {
      bf16x8 a[4], b[4];
#pragma unroll
      for (int t = 0; t < 4; ++t) {
        int row = wm + t * 16 + c;
        int ch = (g + 4 * kc) ^ (row & 7);
        a[t] = *(const bf16x8*)&lA[row * 64 + ch * 8];
      }
#pragma unroll
      for (int t = 0; t < 4; ++t) {
        int row = wn + t * 16 + c;
        int ch = (g + 4 * kc) ^ (row & 7);
        b[t] = *(const bf16x8*)&lB[row * 64 + ch * 8];
      }
#pragma unroll
      for (int i = 0; i < 4; ++i)
#pragma unroll
        for (int j = 0; j < 4; ++j)
          acc[i][j] = MFMA16(a[i], b[j], acc[i][j]);
    }
  }

#pragma unroll
  for (int i = 0; i < 4; ++i)
#pragma unroll
    for (int j = 0; j < 4; ++j)
#pragma unroll
      for (int r = 0; r < 4; ++r) {
        int mm = m0 + wm + i * 16 + g * 4 + r;
        int nn = n0 + wn + j * 16 + c;
        float v = acc[i][j][r] * alpha;
        if (OUTF32)
          ((float*)Cv)[(size_t)mm * N + nn] = v;
        else
          ((u16*)Cv)[(size_t)mm * N + nn] = f32_to_bf16(v);
      }
}

// ---------------- fused flash attention v3 ----------------
// Swapped-operand design: S^T = mfma(K, Q), O^T = mfma(V^T, P^T).
// Q bf16 [2048][2048] (pre-scaled by log2e/sqrt(128)), K bf16 [8192][512],
// VT bf16 [512][8192]. Mask: j <= i + 6144.
// grid 512 = 2 kv-halves x 16 qb(128 rows) x 16 heads; 4 waves x 32 q-rows.
// Partial (unnormalized O^T, m, l) in f32 workspace; merged by attn_merge.
__global__ __launch_bounds__(256, 2)
void attn_kernel(const u16* __restrict__ Q, const u16* __restrict__ Kg,
                 const u16* __restrict__ VT, float* __restrict__ Opart,
                 float* __restrict__ mlp) {
  __shared__ u16 lK[2][64 * 128];       // [j][d], chunk^=(j&15) swizzle
  __shared__ u16 lV[2][128 * 64];       // [d][j], chunk^=(d&7) swizzle
  __shared__ uint32_t lP32[4][16 * 36]; // per-wave P^T pairs [q][jp], pad 36

  const int tid = threadIdx.x;
  const int w = tid >> 6, lane = tid & 63;
  const int c = lane & 15, g = lane >> 4;
  const int bx = blockIdx.x;
  const int h = bx & 15, qb = (bx >> 4) & 15, kvs = bx >> 8;
  const int hk = h >> 2;  // GQA
  const int i0 = qb * 128;
  const int q0 = i0 + w * 32;  // wave's first q row (mt0: q0, mt1: q0+16)

  const int nt = ((i0 + 6271) >> 6) + 1;
  const int nth = nt >> 1;
  const int t0 = kvs ? nth : 0;
  const int ntt = (kvs ? nt : nth) - t0;

  // Q fragments (B-operand): lane holds Q[q=c][d = kc*32 + g*8 .. +7]
  bf16x8 qf0[4], qf1[4];
#pragma unroll
  for (int kc = 0; kc < 4; ++kc) {
    qf0[kc] = *(const bf16x8*)&Q[(size_t)(q0 + c) * 2048 + h * 128 + kc * 32 + g * 8];
    qf1[kc] = *(const bf16x8*)&Q[(size_t)(q0 + 16 + c) * 2048 + h * 128 + kc * 32 + g * 8];
  }

  f32x4 a0[8] = {}, a1[8] = {};  // O^T: lane holds O^T[d=dt*16+g*4+r][q=c]
  float m0s = -1e30f, l0s = 0.f, m1s = -1e30f, l1s = 0.f;

  auto stage = [&](int buf, int t) {
    const int j0 = t << 6;
#pragma unroll
    for (int p = 0; p < 4; ++p) {
      int idx = p * 256 + tid;
      int row = idx >> 4, cc = idx & 15;
      int gc = cc ^ (row & 15);
      ld_lds16(Kg + (size_t)(j0 + row) * 512 + hk * 128 + gc * 8,
               &lK[buf][row * 128 + cc * 8]);
    }
#pragma unroll
    for (int p = 0; p < 4; ++p) {
      int idx = p * 256 + tid;
      int row = idx >> 3, cc = idx & 7;
      int gc = cc ^ (row & 7);
      ld_lds16(VT + (size_t)(hk * 128 + row) * 8192 + j0 + gc * 8,
               &lV[buf][row * 64 + cc * 8]);
    }
  };

  uint32_t* lPw = &lP32[w][0];

  // softmax + P-pack for one m-tile; emits B-frags pb[0..1] for PV
  auto softmax_pb = [&](f32x4 (&sm)[4], float& ms, float& ls, f32x4 (&av)[8],
                        bf16x8 (&pb)[2]) {
    float tm = sm[0][0];
#pragma unroll
    for (int jt = 0; jt < 4; ++jt)
#pragma unroll
      for (int r = 0; r < 4; ++r) tm = fmaxf(tm, sm[jt][r]);
    tm = fmaxf(tm, __shfl_xor(tm, 16));
    tm = fmaxf(tm, __shfl_xor(tm, 32));
    if (!__all(tm - ms <= 8.0f)) {  // defer-max (log2 domain)
      float mnew = fmaxf(ms, tm);
      float al = exp2f(ms - mnew);
      ls *= al; ms = mnew;
#pragma unroll
      for (int dt = 0; dt < 8; ++dt) av[dt] *= al;
    }
    float p_[4][4];
    float ps = 0.f;
#pragma unroll
    for (int jt = 0; jt < 4; ++jt)
#pragma unroll
      for (int r = 0; r < 4; ++r) {
        p_[jt][r] = exp2f(sm[jt][r] - ms);
        ps += p_[jt][r];
      }
    ps += __shfl_xor(ps, 16);
    ps += __shfl_xor(ps, 32);
    ls += ps;
    // pack pairs (j even, j odd) -> u32; write [q=c][jp = jt*8 + g*2 + h]
#pragma unroll
    for (int jt = 0; jt < 4; ++jt) {
      lPw[c * 36 + jt * 8 + g * 2 + 0] = cvt_pk_bf16(p_[jt][0], p_[jt][1]);
      lPw[c * 36 + jt * 8 + g * 2 + 1] = cvt_pk_bf16(p_[jt][2], p_[jt][3]);
    }
    // B-frag: lane needs P^T[j = kc2*32 + g*8 + 0..7][q=c]
    pb[0] = *(const bf16x8*)&lPw[c * 36 + g * 4];
    pb[1] = *(const bf16x8*)&lPw[c * 36 + 16 + g * 4];
  };

  stage(0, t0);

  for (int it = 0; it < ntt; ++it) {
    const int curb = it & 1;
    const int j0 = (t0 + it) << 6;
    if (it + 1 < ntt) {
      stage(curb ^ 1, t0 + it + 1);
      asm volatile("s_waitcnt vmcnt(8)" ::: "memory");
    } else {
      asm volatile("s_waitcnt vmcnt(0)" ::: "memory");
    }
    __builtin_amdgcn_s_barrier();

    // S^T = K Q^T : s[jt] holds S^T[j = jt*16 + g*4 + r][q = c]
    f32x4 s0[4] = {}, s1[4] = {};
    __builtin_amdgcn_s_setprio(1);
#pragma unroll
    for (int kc = 0; kc < 4; ++kc)
#pragma unroll
      for (int jt = 0; jt < 4; ++jt) {
        int row = jt * 16 + c;
        int ch = (g + 4 * kc) ^ (row & 15);
        bf16x8 kf = *(const bf16x8*)&lK[curb][row * 128 + ch * 8];
        s0[jt] = MFMA16(kf, qf0[kc], s0[jt]);
        s1[jt] = MFMA16(kf, qf1[kc], s1[jt]);
      }
    __builtin_amdgcn_s_setprio(0);

    if (j0 + 63 > q0 + 6144) {  // boundary tiles: causal-offset mask
#pragma unroll
      for (int jt = 0; jt < 4; ++jt)
#pragma unroll
        for (int r = 0; r < 4; ++r) {
          int jg = j0 + jt * 16 + g * 4 + r;
          if (jg > q0 + c + 6144) s0[jt][r] = -1e30f;
          if (jg > q0 + 16 + c + 6144) s1[jt][r] = -1e30f;
        }
    }

    bf16x8 pb0[2], pb1[2];
    softmax_pb(s0, m0s, l0s, a0, pb0);
    softmax_pb(s1, m1s, l1s, a1, pb1);

    // O^T += V^T P^T : vf shared across both m-tiles
    __builtin_amdgcn_s_setprio(1);
#pragma unroll
    for (int dt = 0; dt < 8; ++dt)
#pragma unroll
      for (int kc2 = 0; kc2 < 2; ++kc2) {
        int row = dt * 16 + c;
        int vch = (g + 4 * kc2) ^ (row & 7);
        bf16x8 vf = *(const bf16x8*)&lV[curb][row * 64 + vch * 8];
        a0[dt] = MFMA16(vf, pb0[kc2], a0[dt]);
        a1[dt] = MFMA16(vf, pb1[kc2], a1[dt]);
      }
    __builtin_amdgcn_s_setprio(0);

    __builtin_amdgcn_s_barrier();
  }

  // epilogue: store unnormalized partials (f32) + (m,l)
  const size_t pbase = ((size_t)(kvs * 16 + h) * 16 + qb);
  float* Op = Opart + pbase * 16384;
  float* mlb = mlp + pbase * 256;
  const int qi0 = w * 32 + c;
#pragma unroll
  for (int dt = 0; dt < 8; ++dt) {
    *(f32x4*)&Op[(size_t)qi0 * 128 + dt * 16 + g * 4] = a0[dt];
    *(f32x4*)&Op[(size_t)(qi0 + 16) * 128 + dt * 16 + g * 4] = a1[dt];
  }
  if (g == 0) {
    mlb[qi0] = m0s;
    mlb[128 + qi0] = l0s;
    mlb[qi0 + 16] = m1s;
    mlb[128 + qi0 + 16] = l1s;
  }
}

// ---------------- merge the two KV-half partials ----------------
__global__ __launch_bounds__(256)
void attn_merge(const float* __restrict__ Opart, const float* __restrict__ mlp,
                u16* __restrict__ O) {
  const int bx = blockIdx.x;  // h*16 + qb
  const int h = bx >> 4, qb = bx & 15;
  const int q = threadIdx.x & 127, hf = threadIdx.x >> 7;
  const size_t p0 = ((size_t)(0 + h) * 16 + qb);
  const size_t p1 = ((size_t)(16 + h) * 16 + qb);
  float mm0 = mlp[p0 * 256 + q], ll0 = mlp[p0 * 256 + 128 + q];
  float mm1 = mlp[p1 * 256 + q], ll1 = mlp[p1 * 256 + 128 + q];
  float m = fmaxf(mm0, mm1);
  float w0 = exp2f(mm0 - m), w1 = exp2f(mm1 - m);
  float inv = 1.f / (ll0 * w0 + ll1 * w1);
  const float* A = Opart + p0 * 16384 + (size_t)q * 128 + hf * 64;
  const float* B = Opart + p1 * 16384 + (size_t)q * 128 + hf * 64;
  u16* out = O + (size_t)(qb * 128 + q) * 2048 + h * 128 + hf * 64;
#pragma unroll
  for (int d = 0; d < 64; d += 4) {
    float4 a = *(const float4*)&A[d];
    float4 b = *(const float4*)&B[d];
    ushort4 o;
    o.x = f32_to_bf16((a.x * w0 + b.x * w1) * inv);
    o.y = f32_to_bf16((a.y * w0 + b.y * w1) * inv);
    o.z = f32_to_bf16((a.z * w0 + b.z * w1) * inv);
    o.w = f32_to_bf16((a.w * w0 + b.w * w1) * inv);
    *(ushort4*)&out[d] = o;
  }
}

// ---------------- launch ----------------
extern "C" void kernel_launch(void* const* d_in, const int* in_sizes, int n_in,
                              void* d_out, int out_size, void* d_ws, size_t ws_size,
                              hipStream_t stream) {
  (void)in_sizes; (void)n_in; (void)out_size; (void)ws_size;
  const float* xq = (const float*)d_in[0];   // [2048][2048]
  const float* xkv = (const float*)d_in[1];  // [8192][2048]
  const float* Wq = (const float*)d_in[2];   // [2048][2048]
  const float* Wk = (const float*)d_in[3];   // [512][2048]
  const float* Wv = (const float*)d_in[4];   // [512][2048]
  const float* Wo = (const float*)d_in[5];   // [2048][2048]

  u16* ws = (u16*)d_ws;
  const size_t M1 = 1024 * 1024;
  u16* xq_b  = ws;             // 4M elems (8MB)   -- dead after input GEMMs
  u16* xkv_b = ws + 4 * M1;    // 16M (32MB)       -- dead after input GEMMs
  u16* wq_b  = ws + 20 * M1;   // 4M
  u16* wk_b  = ws + 24 * M1;   // 1M
  u16* wv_b  = ws + 25 * M1;   // 1M
  u16* wo_b  = ws + 26 * M1;   // 4M
  u16* Qb    = ws + 30 * M1;   // 4M  (pre-scaled by log2e/sqrt(D))
  u16* Kb    = ws + 34 * M1;   // 4M  [8192][512]
  u16* VTb   = ws + 38 * M1;   // 4M  [512][8192]
  u16* Ob    = ws + 42 * M1;   // 4M
  // attn partials alias the dead xq_b/xkv_b region (34.1MB <= 40MB)
  float* Opart = (float*)d_ws;            // 2*16*16*128*128 f32
  float* mlptr = Opart + 8388608;         // 2*16*16*256 f32

  cvt_bf16<<<1024, 256, 0, stream>>>(xq, xq_b, (int)(4 * M1 / 4));
  cvt_bf16<<<1024, 256, 0, stream>>>(xkv, xkv_b, (int)(16 * M1 / 4));
  cvt_bf16<<<1024, 256, 0, stream>>>(Wq, wq_b, (int)(4 * M1 / 4));
  cvt_bf16<<<1024, 256, 0, stream>>>(Wk, wk_b, (int)(1 * M1 / 4));
  cvt_bf16<<<1024, 256, 0, stream>>>(Wv, wv_b, (int)(1 * M1 / 4));
  cvt_bf16<<<1024, 256, 0, stream>>>(Wo, wo_b, (int)(4 * M1 / 4));

  // Q = x_q Wq^T (scaled);  K = x_kv Wk^T;  V^T = Wv x_kv^T (operand swap)
  gemm_nt<0><<<dim3(16, 16), 256, 0, stream>>>(xq_b, wq_b, Qb, 2048, 2048, 2048, 0.12751743f);
  gemm_nt<0><<<dim3(4, 64), 256, 0, stream>>>(xkv_b, wk_b, Kb, 8192, 512, 2048, 1.0f);
  gemm_nt<0><<<dim3(64, 4), 256, 0, stream>>>(wv_b, xkv_b, VTb, 512, 8192, 2048, 1.0f);

  attn_kernel<<<512, 256, 0, stream>>>(Qb, Kb, VTb, Opart, mlptr);
  attn_merge<<<256, 256, 0, stream>>>(Opart, mlptr, Ob);

  // out = O Wo^T (f32 output)
  gemm_nt<1><<<dim3(16, 16), 256, 0, stream>>>(Ob, wo_b, d_out, 2048, 2048, 2048, 1.0f);
}